// Round 1
// baseline (68.680 us; speedup 1.0000x reference)
//
#include <hip/hip_runtime.h>
#include <math.h>

#define KB_CONST 8.62e-05f
#define EPS0_DOT 1.0e4f
#define PARAM_M 2.733f

// GROUP_IDX from counts [1,2,8,7,6,9,17]
__constant__ unsigned char c_group_idx[50] = {
    0,
    1,1,
    2,2,2,2,2,2,2,2,
    3,3,3,3,3,3,3,
    4,4,4,4,4,4,
    5,5,5,5,5,5,5,5,5,
    6,6,6,6,6,6,6,6,6,6,6,6,6,6,6,6,6
};

// triu_indices(6) in row-major order (21 pairs)
__constant__ unsigned char c_iu[21] = {0,0,0,0,0,0, 1,1,1,1,1, 2,2,2,2, 3,3,3, 4,4, 5};
__constant__ unsigned char c_ju[21] = {0,1,2,3,4,5, 1,2,3,4,5, 2,3,4,5, 3,4,5, 4,5, 5};

__global__ __launch_bounds__(64) void yield_stress_kernel(
    const float* __restrict__ lsr,        // (50,6)
    const float* __restrict__ temp,       // (50,)
    const float* __restrict__ srate,      // (50,)
    const float* __restrict__ grain,      // (50,)
    const float* __restrict__ w21,        // (21,)
    const float* __restrict__ raw_dH,     // (7,6)
    const float* __restrict__ raw_KHP,    // (7,)
    float* __restrict__ out)              // (50,)
{
    __shared__ float sW[6][6];     // symmetric weight matrix
    __shared__ float sdH[7][6];    // constrained deltaH
    __shared__ float sKHP[7];      // constrained KHP

    const int t = threadIdx.x;

    // Build symmetric weight matrix: 0.1 + exp(w21), scattered to (iu,ju) and (ju,iu)
    if (t < 21) {
        float v = 0.1f + __expf(w21[t]) ;
        // use precise expf to match numpy closely
        v = 0.1f + expf(w21[t]);
        int i = c_iu[t], j = c_ju[t];
        sW[i][j] = v;
        sW[j][i] = v;
    }
    // param_deltaH = 0.1 + 4.9*sigmoid(raw)
    if (t < 42) {
        float x = raw_dH[t];
        float sig = 1.0f / (1.0f + expf(-x));
        sdH[t / 6][t % 6] = 0.1f + 4.9f * sig;
    }
    // param_KHP = exp(raw)
    if (t < 7) {
        sKHP[t] = expf(raw_KHP[t]);
    }
    __syncthreads();

    if (t < 50) {
        const int g = c_group_idx[t];
        const float T = temp[t];
        const float S = srate[t];
        const float G = grain[t];

        // c = KB * T * log(EPS0_DOT / S)   (positive: S <= ~100 < 1e4)
        const float cfac = KB_CONST * T * logf(EPS0_DOT / S);

        // Load this row of LSR
        float r0 = lsr[t * 6 + 0];
        float r1 = lsr[t * 6 + 1];
        float r2 = lsr[t * 6 + 2];
        float r3 = lsr[t * 6 + 3];
        float r4 = lsr[t * 6 + 4];
        float r5 = lsr[t * 6 + 5];

        const float expo = (float)(2.0 / 3.0);

        float tau = 0.0f;
        #pragma unroll
        for (int j = 0; j < 6; ++j) {
            // A[t][j] = sum_k LSR[t][k] * W[k][j]
            float a = r0 * sW[0][j] + r1 * sW[1][j] + r2 * sW[2][j]
                    + r3 * sW[3][j] + r4 * sW[4][j] + r5 * sW[5][j];
            float therm = cfac / sdH[g][j];
            float p = powf(therm, expo);
            tau += a * (1.0f - p);
        }

        out[t] = tau * PARAM_M + sKHP[g] / sqrtf(G);
    }
}

extern "C" void kernel_launch(void* const* d_in, const int* in_sizes, int n_in,
                              void* d_out, int out_size, void* d_ws, size_t ws_size,
                              hipStream_t stream) {
    const float* lsr     = (const float*)d_in[0];  // (50,6)
    const float* temp    = (const float*)d_in[1];  // (50,)
    const float* srate   = (const float*)d_in[2];  // (50,)
    const float* grain   = (const float*)d_in[3];  // (50,)
    const float* w21     = (const float*)d_in[4];  // (21,)
    const float* raw_dH  = (const float*)d_in[5];  // (7,6)
    const float* raw_KHP = (const float*)d_in[6];  // (7,)
    float* out = (float*)d_out;                    // (50,)

    yield_stress_kernel<<<1, 64, 0, stream>>>(lsr, temp, srate, grain,
                                              w21, raw_dH, raw_KHP, out);
}